// Round 7
// baseline (338.911 us; speedup 1.0000x reference)
//
#include <hip/hip_runtime.h>
#include <math.h>

#define NB 4096
#define NR 49
#define NS 50
#define ND 512
#define NK 100
#define NTT 8           // N-tiles of 16 cols, padded (128 >= 100; tiles 6,7 partially/fully zero)
#define KSTEPS 16       // 512 / 32 (global k-steps)
#define CHUNK_KS 8      // k-steps per LDS chunk (256 cols)
#define FRAGS (NTT * KSTEPS * 64 * 8)   // 65536 ushorts (131072 B) per weight matrix

typedef __attribute__((ext_vector_type(8))) short short8;
typedef __attribute__((ext_vector_type(4))) float f32x4;

__device__ __forceinline__ unsigned short f32_bf16(float f) {
    union { float f; unsigned u; } x; x.f = f;
    return (unsigned short)((x.u + 0x7fffu + ((x.u >> 16) & 1u)) >> 16);  // RNE
}
__device__ __forceinline__ unsigned cvt_pk_bf16(float lo, float hi) {
    unsigned r;
    asm("v_cvt_pk_bf16_f32 %0, %1, %2" : "=v"(r) : "v"(lo), "v"(hi));
    return r;
}
__device__ __forceinline__ float fast_tanh(float x) {
    const float ax = fabsf(x);
    const float e = __expf(2.f * ax);            // inf for large ax -> r = 1
    const float r = 1.f - 2.f / (e + 1.f);
    return copysignf(r, x);
}

// ---------------------------------------------------------------------------
// Pre-pass: 2 weight matrices [512][100] f32 -> bf16 MFMA B-fragments
// (cols 100..127 zero-padded). Only w_Vi_0 / w_Vt_1 needed: broadcast
// conditioning branches cancel in softmax; the two passes are independent.
// frag(t, gk): lane l holds W[k = gk*32 + (l>>4)*8 + j][col = t*16 + (l&15)].
// ---------------------------------------------------------------------------
__global__ void preswz_kernel(const float* __restrict__ w0, const float* __restrict__ w1,
                              unsigned short* __restrict__ ws)
{
    const int l  = threadIdx.x;          // 64
    const int gk = blockIdx.x & 15;
    const int t  = blockIdx.x >> 4;      // 0..7
    const int m  = blockIdx.y;           // 0..1
    const float* W = m ? w1 : w0;
    const int col = t * 16 + (l & 15);
    const int k0  = gk * 32 + (l >> 4) * 8;
    unsigned short* o = ws + (size_t)m * FRAGS + ((size_t)(t * 16 + gk) * 64 + l) * 8;
#pragma unroll
    for (int j = 0; j < 8; ++j) {
        float v = (col < NK) ? W[(size_t)(k0 + j) * NK + col] : 0.f;
        o[j] = f32_bf16(v);
    }
}

// ---------------------------------------------------------------------------
// Main kernel: one block per (batch, pass), 512 threads (8 waves), 4 blocks/CU.
// Each block: stage features -> GEMM scores -> softmax -> weighted sum ->
// atomicAdd into out (pre-zeroed; 2 commutative f32 adds = deterministic).
// ---------------------------------------------------------------------------
struct SM {
    short buf[NS * 256];     // 25600 B: bf16 feature K-chunk [50 rows][256 cols]
    float scores[64];        // row partials n-half 0 (incl. bias)
    float part2[64];         // row partials n-half 1
    float P[64];
};

__global__ __launch_bounds__(512, 8) void coattn_main(
    const float* __restrict__ ifeat, const float* __restrict__ tfeat,
    const float* __restrict__ wPi0, const float* __restrict__ bPi0,
    const float* __restrict__ wPi1, const float* __restrict__ bPi1,
    const unsigned short* __restrict__ wsW, float* __restrict__ out)
{
    __shared__ SM sm;
    const int pass = blockIdx.x & 1;
    const int b    = blockIdx.x >> 1;
    const int tid  = threadIdx.x;

    const float* feat = pass ? (tfeat + (size_t)b * NS * ND) : (ifeat + (size_t)b * NR * ND);
    const int nrows  = pass ? NS : NR;
    const int nclamp = nrows - 1;
    const unsigned short* wsR = wsW + (size_t)pass * FRAGS;
    const float* wPiRow = pass ? (wPi1 + NK) : wPi0;
    const float* bvec   = pass ? bPi1 : bPi0;

    const int lane = tid & 63, wid = tid >> 6;
    const int m = wid & 3, nh = wid >> 2;
    const int t0 = nh * 4;                               // 4 tiles per n-half (padded)
    const int colg = lane & 15, g = lane >> 4;
    const int arow0 = m * 16 + colg;
    const int arow = (arow0 < nclamp) ? arow0 : nclamp;  // clamp padded rows
    const int rswz = arow & 7;

    const unsigned short* wlane = wsR + (size_t)t0 * (KSTEPS * 512) + lane * 8;

    const f32x4 zero4 = {0.f, 0.f, 0.f, 0.f};
    f32x4 acc[4] = {zero4, zero4, zero4, zero4};

    const int nitems = nrows * 32;

    for (int chunk = 0; chunk < 2; ++chunk) {
        __syncthreads();   // buf free (prior chunk's GEMM done)
        // ---- stage chunk: global f32 -> bf16 LDS, 16B-chunk XOR swizzle
        for (int it = tid; it < nitems; it += 512) {
            const int r = it >> 5, c = it & 31;
            const float* p = feat + (r << 9) + (chunk << 8) + (c << 3);
            const float4 a  = *reinterpret_cast<const float4*>(p);
            const float4 b4 = *reinterpret_cast<const float4*>(p + 4);
            uint4 v;
            v.x = cvt_pk_bf16(a.x, a.y);   v.y = cvt_pk_bf16(a.z, a.w);
            v.z = cvt_pk_bf16(b4.x, b4.y); v.w = cvt_pk_bf16(b4.z, b4.w);
            *reinterpret_cast<uint4*>(&sm.buf[(r << 8) + ((c ^ (r & 7)) << 3)]) = v;
        }
        __syncthreads();

        // ---- GEMM on this chunk: 8 k-steps x 4 tiles (scheduler-managed loads)
        const int gk0 = chunk * CHUNK_KS;
#pragma unroll
        for (int ks = 0; ks < CHUNK_KS; ++ks) {
            const short8 a = *reinterpret_cast<const short8*>(
                &sm.buf[(arow << 8) + ((((ks << 2) + g) ^ rswz) << 3)]);
            const unsigned short* wk = wlane + (size_t)(gk0 + ks) * 512;
#pragma unroll
            for (int q = 0; q < 4; ++q) {
                const short8 w = *reinterpret_cast<const short8*>(wk + (size_t)q * (KSTEPS * 512));
                acc[q] = __builtin_amdgcn_mfma_f32_16x16x32_bf16(a, w, acc[q], 0, 0, 0);
            }
        }
    }

    // ---- epilogue: s[row] = sum_cols tanh(D) * wPiRow; shfl-reduce 16 col-lanes
    {
        float s[4] = {0.f, 0.f, 0.f, 0.f};
#pragma unroll
        for (int q = 0; q < 4; ++q) {
            const int col = (t0 + q) * 16 + colg;
            const float w = (col < NK) ? wPiRow[col] : 0.f;
#pragma unroll
            for (int i = 0; i < 4; ++i) s[i] += fast_tanh(acc[q][i]) * w;
        }
#pragma unroll
        for (int off = 1; off < 16; off <<= 1) {
#pragma unroll
            for (int i = 0; i < 4; ++i) s[i] += __shfl_xor(s[i], off);
        }
        if (colg == 0) {
            float* o = nh ? sm.part2 : sm.scores;
            const int rbase = m * 16 + g * 4;
#pragma unroll
            for (int i = 0; i < 4; ++i) {
                const int r = rbase + i;
                if (r < nrows) o[r] = s[i] + (nh ? 0.f : bvec[r]);
            }
        }
    }
    __syncthreads();

    if (tid < 64) {   // softmax over rows
        const float v = (tid < nrows) ? sm.scores[tid] + sm.part2[tid] : -3.0e38f;
        float mx = v;
#pragma unroll
        for (int off = 32; off; off >>= 1) mx = fmaxf(mx, __shfl_xor(mx, off));
        const float e = (tid < nrows) ? __expf(v - mx) : 0.f;
        float su = e;
#pragma unroll
        for (int off = 32; off; off >>= 1) su += __shfl_xor(su, off);
        sm.P[tid] = e / su;
    }
    __syncthreads();

    // ---- weighted sum: V[tid] = sum_r P[r] * feat[r, tid]  (global f32, L2/L3-hot)
    {
        float v = 0.f;
        const float* fp = feat + tid;
        for (int r = 0; r < nrows; ++r) v += sm.P[r] * fp[r << 9];
        atomicAdd(&out[(size_t)b * ND + tid], v);
    }
}

extern "C" void kernel_launch(void* const* d_in, const int* in_sizes, int n_in,
                              void* d_out, int out_size, void* d_ws, size_t ws_size,
                              hipStream_t stream) {
    const float* ifeat = (const float*)d_in[0];
    const float* tfeat = (const float*)d_in[1];
    const float* wVi0  = (const float*)d_in[2];
    const float* wPi0  = (const float*)d_in[4];
    const float* bPi0  = (const float*)d_in[5];
    const float* wVt1  = (const float*)d_in[7];
    const float* wPi1  = (const float*)d_in[8];
    const float* bPi1  = (const float*)d_in[9];
    float* outp = (float*)d_out;
    unsigned short* wsW = (unsigned short*)d_ws;   // 2*131072 = 262144 B

    hipMemsetAsync(outp, 0, (size_t)NB * ND * sizeof(float), stream);
    hipLaunchKernelGGL(preswz_kernel, dim3(NTT * KSTEPS, 2), dim3(64), 0, stream,
                       wVi0, wVt1, wsW);
    hipLaunchKernelGGL(coattn_main, dim3(2 * NB), dim3(512), 0, stream,
                       ifeat, tfeat, wPi0, bPi0, wPi1, bPi1, wsW, outp);
}